// Round 1
// baseline (3064.006 us; speedup 1.0000x reference)
//
#include <hip/hip_runtime.h>
#include <hip/hip_bf16.h>
#include <math.h>

// Problem constants
#define B_   8
#define N_   2000
#define C_   512
#define H_   8
#define W_   5
#define SR_  2
#define M_   1000      // N/SR
#define G_   400       // N/W
#define HD_  64        // C/H
#define LN_EPS_ 1e-5f
#define SCALE_  0.125f // hd^-0.5

__device__ __forceinline__ float wave_max(float v) {
#pragma unroll
  for (int o = 32; o > 0; o >>= 1) v = fmaxf(v, __shfl_xor(v, o));
  return v;
}
__device__ __forceinline__ float wave_sum(float v) {
#pragma unroll
  for (int o = 32; o > 0; o >>= 1) v += __shfl_xor(v, o);
  return v;
}

// Y[r,o] = sum_k X[r,k] * Wm[o,k] + bias[o]
// X: (R,K) row-major, Wm: (O,K) row-major. R%64==0, O%64==0, K%32==0.
__global__ __launch_bounds__(256) void gemm_nt(const float* __restrict__ X,
                                               const float* __restrict__ Wm,
                                               const float* __restrict__ bias,
                                               float* __restrict__ Y,
                                               int R, int K, int O) {
  __shared__ float Xs[32][65];
  __shared__ float Ws[32][65];
  const int tid = threadIdx.x;
  const long r0 = (long)blockIdx.y * 64;
  const long o0 = (long)blockIdx.x * 64;
  const int tr = tid >> 4;   // 0..15
  const int tc = tid & 15;   // 0..15
  float acc[4][4] = {};
  for (int k0 = 0; k0 < K; k0 += 32) {
#pragma unroll
    for (int i = 0; i < 2; ++i) {
      int f = tid + i * 256;        // 0..511 float4 slots (64 rows x 8)
      int row = f >> 3;
      int kq  = f & 7;
      float4 vx = *reinterpret_cast<const float4*>(X + (r0 + row) * K + k0 + kq * 4);
      Xs[kq*4+0][row] = vx.x; Xs[kq*4+1][row] = vx.y;
      Xs[kq*4+2][row] = vx.z; Xs[kq*4+3][row] = vx.w;
      float4 vw = *reinterpret_cast<const float4*>(Wm + (o0 + row) * K + k0 + kq * 4);
      Ws[kq*4+0][row] = vw.x; Ws[kq*4+1][row] = vw.y;
      Ws[kq*4+2][row] = vw.z; Ws[kq*4+3][row] = vw.w;
    }
    __syncthreads();
#pragma unroll
    for (int k = 0; k < 32; ++k) {
      float xr[4], wc[4];
#pragma unroll
      for (int i = 0; i < 4; ++i) xr[i] = Xs[k][tr + 16*i];
#pragma unroll
      for (int j = 0; j < 4; ++j) wc[j] = Ws[k][tc + 16*j];
#pragma unroll
      for (int i = 0; i < 4; ++i)
#pragma unroll
        for (int j = 0; j < 4; ++j) acc[i][j] = fmaf(xr[i], wc[j], acc[i][j]);
    }
    __syncthreads();
  }
#pragma unroll
  for (int i = 0; i < 4; ++i) {
    long r = r0 + tr + 16*i;
#pragma unroll
    for (int j = 0; j < 4; ++j) {
      long o = o0 + tc + 16*j;
      Y[r * O + o] = acc[i][j] + bias[o];
    }
  }
}

// Xp[b*M+m][c] = 0.5*(x[b,2m,c] + x[b,2m+1,c])
__global__ void pool_mean(const float* __restrict__ X, float* __restrict__ Xp) {
  int idx = blockIdx.x * 256 + threadIdx.x;
  const int total = B_ * M_ * (C_ / 4);
  if (idx >= total) return;
  int row = idx / (C_ / 4);
  int cq  = idx % (C_ / 4);
  int b = row / M_, m = row % M_;
  const float4 va = reinterpret_cast<const float4*>(X + ((size_t)b * N_ + 2*m)     * C_)[cq];
  const float4 vb = reinterpret_cast<const float4*>(X + ((size_t)b * N_ + 2*m + 1) * C_)[cq];
  float4 r;
  r.x = 0.5f * (va.x + vb.x); r.y = 0.5f * (va.y + vb.y);
  r.z = 0.5f * (va.z + vb.z); r.w = 0.5f * (va.w + vb.w);
  reinterpret_cast<float4*>(Xp + (size_t)row * C_)[cq] = r;
}

// in-place LayerNorm + exact GELU over rows of length 512
__global__ __launch_bounds__(256) void ln_gelu_inplace(float* __restrict__ Xc,
                                                       const float* __restrict__ gam,
                                                       const float* __restrict__ bet) {
  const int row = blockIdx.x;
  float* p = Xc + (size_t)row * C_;
  const int t = threadIdx.x;
  float v0 = p[t], v1 = p[t + 256];
  float s  = wave_sum(v0 + v1);
  float ss = wave_sum(v0 * v0 + v1 * v1);
  __shared__ float rs[4], rss[4];
  const int w = t >> 6, lane = t & 63;
  if (lane == 0) { rs[w] = s; rss[w] = ss; }
  __syncthreads();
  float ts  = rs[0] + rs[1] + rs[2] + rs[3];
  float tss = rss[0] + rss[1] + rss[2] + rss[3];
  float mean = ts * (1.0f / C_);
  float var  = tss * (1.0f / C_) - mean * mean;
  float rstd = rsqrtf(var + LN_EPS_);
  float u0 = (v0 - mean) * rstd * gam[t]       + bet[t];
  float u1 = (v1 - mean) * rstd * gam[t + 256] + bet[t + 256];
  p[t]       = u0 * 0.5f * (1.0f + erff(u0 * 0.70710678118654752f));
  p[t + 256] = u1 * 0.5f * (1.0f + erff(u1 * 0.70710678118654752f));
}

// Fused attention. Block = 256 thr = 4 waves; handles (b, h, 4 consecutive queries).
// Q:   (B,N,C)   q at channel h*64+d  (unscaled)
// KV:  (B,N,2C)  local k at h*64+d, v at C+h*64+d
// KVP: (B,M,2C)  pooled k/v same layout
// Oa:  (B,N,C)
__global__ __launch_bounds__(256) void attn_fused(const float* __restrict__ Q,
                                                  const float* __restrict__ KV,
                                                  const float* __restrict__ KVP,
                                                  float* __restrict__ Oa) {
  __shared__ float Ks[64][65];
  __shared__ float Vs[64][65];
  __shared__ float qs[4][64];
  __shared__ float ps[4][64];
  const int bid = blockIdx.x;
  const int b  = bid / (H_ * (N_ / 4));
  const int h  = (bid / (N_ / 4)) % H_;
  const int n0 = (bid % (N_ / 4)) * 4;
  const int tid  = threadIdx.x;
  const int w    = tid >> 6;
  const int lane = tid & 63;
  const int n = n0 + w;
  const int g = n / W_;

  qs[w][lane] = Q[((size_t)(b * N_ + n)) * C_ + h * HD_ + lane] * SCALE_;
  __syncthreads();

  // ---- local phase: 5 keys of this query's window ----
  float m_cur, l_run, acc;
  {
    float s = -3.0e38f;
    if (lane < W_) {
      const float* kp = KV + ((size_t)b * N_ + (size_t)g * W_ + lane) * (2 * C_) + h * HD_;
      float t = 0.f;
#pragma unroll
      for (int d = 0; d < HD_; ++d) t = fmaf(qs[w][d], kp[d], t);
      s = t;
    }
    m_cur = wave_max(s);
    float p = (lane < W_) ? expf(s - m_cur) : 0.f;
    l_run = wave_sum(p);
    ps[w][lane] = p;   // same-wave LDS: ordered, no barrier needed
    acc = 0.f;
#pragma unroll
    for (int j = 0; j < W_; ++j) {
      float vj = KV[((size_t)b * N_ + (size_t)g * W_ + j) * (2 * C_) + C_ + h * HD_ + lane];
      acc = fmaf(ps[w][j], vj, acc);
    }
  }

  // ---- pooled phase: online softmax over 1000 keys in blocks of 64 ----
  const float* kvp_b = KVP + (size_t)b * M_ * (2 * C_);
  for (int jb = 0; jb < (M_ + 63) / 64; ++jb) {
    __syncthreads();   // previous-iteration Ks/Vs consumers done
#pragma unroll
    for (int i = 0; i < 4; ++i) {
      int f = tid + i * 256;     // 0..1023 float4 slots (64 rows x 16)
      int row = f >> 4;
      int dq  = f & 15;
      int m   = jb * 64 + row;
      float4 kk = make_float4(0.f, 0.f, 0.f, 0.f);
      float4 vv = make_float4(0.f, 0.f, 0.f, 0.f);
      if (m < M_) {
        kk = *reinterpret_cast<const float4*>(kvp_b + (size_t)m * (2 * C_) + h * HD_ + dq * 4);
        vv = *reinterpret_cast<const float4*>(kvp_b + (size_t)m * (2 * C_) + C_ + h * HD_ + dq * 4);
      }
      Ks[row][dq*4+0] = kk.x; Ks[row][dq*4+1] = kk.y;
      Ks[row][dq*4+2] = kk.z; Ks[row][dq*4+3] = kk.w;
      Vs[row][dq*4+0] = vv.x; Vs[row][dq*4+1] = vv.y;
      Vs[row][dq*4+2] = vv.z; Vs[row][dq*4+3] = vv.w;
    }
    __syncthreads();

    int m_idx = jb * 64 + lane;
    float s = -3.0e38f;
    if (m_idx < M_) {
      float t = 0.f;
#pragma unroll
      for (int d = 0; d < HD_; ++d) t = fmaf(qs[w][d], Ks[lane][d], t);
      s = t;
    }
    float bm    = wave_max(s);
    float m_new = fmaxf(m_cur, bm);
    float alpha = expf(m_cur - m_new);
    float p = (m_idx < M_) ? expf(s - m_new) : 0.f;
    l_run = l_run * alpha + wave_sum(p);
    acc *= alpha;
    ps[w][lane] = p;
#pragma unroll 8
    for (int j = 0; j < 64; ++j) acc = fmaf(ps[w][j], Vs[j][lane], acc);
    m_cur = m_new;
  }
  Oa[((size_t)(b * N_ + n)) * C_ + h * HD_ + lane] = acc / l_run;
}

extern "C" void kernel_launch(void* const* d_in, const int* in_sizes, int n_in,
                              void* d_out, int out_size, void* d_ws, size_t ws_size,
                              hipStream_t stream) {
  const float* x   = (const float*)d_in[0];
  const float* Wq  = (const float*)d_in[1];
  const float* bq  = (const float*)d_in[2];
  const float* Wkv = (const float*)d_in[3];
  const float* bkv = (const float*)d_in[4];
  const float* Wc  = (const float*)d_in[5];
  const float* bc  = (const float*)d_in[6];
  const float* lng = (const float*)d_in[7];
  const float* lnb = (const float*)d_in[8];
  const float* Wp  = (const float*)d_in[9];
  const float* bp  = (const float*)d_in[10];
  float* out = (float*)d_out;

  float* ws     = (float*)d_ws;
  float* q_buf  = ws;                              // 16000*512
  float* kv_buf = q_buf  + (size_t)16000 * 512;    // 16000*1024
  float* xpool  = kv_buf + (size_t)16000 * 1024;   // 8000*512
  float* xc     = xpool  + (size_t)8000  * 512;    // 8000*512
  float* kvp    = xc     + (size_t)8000  * 512;    // 8000*1024
  float* aout   = kvp    + (size_t)8000  * 1024;   // 16000*512

  dim3 blk(256);

  // pooled pre-path
  pool_mean<<<dim3((B_ * M_ * (C_/4) + 255) / 256), blk, 0, stream>>>(x, xpool);
  gemm_nt<<<dim3(C_/64, (B_*M_)/64), blk, 0, stream>>>(xpool, Wc, bc, xc, B_*M_, C_, C_);
  ln_gelu_inplace<<<dim3(B_*M_), blk, 0, stream>>>(xc, lng, lnb);
  gemm_nt<<<dim3((2*C_)/64, (B_*M_)/64), blk, 0, stream>>>(xc, Wkv, bkv, kvp, B_*M_, C_, 2*C_);

  // main projections
  gemm_nt<<<dim3(C_/64, (B_*N_)/64), blk, 0, stream>>>(x, Wq, bq, q_buf, B_*N_, C_, C_);
  gemm_nt<<<dim3((2*C_)/64, (B_*N_)/64), blk, 0, stream>>>(x, Wkv, bkv, kv_buf, B_*N_, C_, 2*C_);

  // fused attention (local 5 + pooled 1000, online softmax)
  attn_fused<<<dim3(B_ * H_ * (N_ / 4)), blk, 0, stream>>>(q_buf, kv_buf, kvp, aout);

  // output projection
  gemm_nt<<<dim3(C_/64, (B_*N_)/64), blk, 0, stream>>>(aout, Wp, bp, out, B_*N_, C_, C_);
}

// Round 2
// 1068.962 us; speedup vs baseline: 2.8663x; 2.8663x over previous
//
#include <hip/hip_runtime.h>
#include <hip/hip_bf16.h>
#include <math.h>

// Problem constants
#define B_   8
#define N_   2000
#define C_   512
#define H_   8
#define W_   5
#define SR_  2
#define M_   1000      // N/SR
#define HD_  64        // C/H
#define LN_EPS_ 1e-5f
#define SCALE_  0.125f // hd^-0.5

// attention tiling
#define TQ_   80       // q rows per block (lcm(5,16)) -> 25 tiles, no remainder
#define NW_   5        // waves per block (16 q rows each)
#define KSTR  72       // Ks/Qs LDS row stride in bf16 (16B aligned, even bank spread)
#define VSTR  104      // Vt LDS row stride in bf16
#define PSTR  104      // P LDS row stride in bf16

typedef __attribute__((ext_vector_type(8))) short bf16x8;
typedef __attribute__((ext_vector_type(4))) float f32x4;
#define MFMA16(a,b,c) __builtin_amdgcn_mfma_f32_16x16x32_bf16(a,b,c,0,0,0)

__device__ __forceinline__ short f2bf(float f) {
  unsigned u = __float_as_uint(f);
  u += 0x7FFFu + ((u >> 16) & 1u);
  return (short)(u >> 16);
}
__device__ __forceinline__ float bf2f(short s) {
  return __uint_as_float(((unsigned)(unsigned short)s) << 16);
}
__device__ __forceinline__ uint2 pack4bf(float4 v) {
  unsigned a = ((unsigned)(unsigned short)f2bf(v.x)) | (((unsigned)(unsigned short)f2bf(v.y)) << 16);
  unsigned b = ((unsigned)(unsigned short)f2bf(v.z)) | (((unsigned)(unsigned short)f2bf(v.w)) << 16);
  return make_uint2(a, b);
}
__device__ __forceinline__ int div5(int x) { return (x * 205) >> 10; }  // exact for x < 1024

__device__ __forceinline__ float wave_max(float v) {
#pragma unroll
  for (int o = 32; o > 0; o >>= 1) v = fmaxf(v, __shfl_xor(v, o));
  return v;
}
__device__ __forceinline__ float wave_sum(float v) {
#pragma unroll
  for (int o = 32; o > 0; o >>= 1) v += __shfl_xor(v, o);
  return v;
}

// ---------------- fp32 GEMM (unchanged this round) ----------------
__global__ __launch_bounds__(256) void gemm_nt(const float* __restrict__ X,
                                               const float* __restrict__ Wm,
                                               const float* __restrict__ bias,
                                               float* __restrict__ Y,
                                               int R, int K, int O) {
  __shared__ float Xs[32][65];
  __shared__ float Ws[32][65];
  const int tid = threadIdx.x;
  const long r0 = (long)blockIdx.y * 64;
  const long o0 = (long)blockIdx.x * 64;
  const int tr = tid >> 4;
  const int tc = tid & 15;
  float acc[4][4] = {};
  for (int k0 = 0; k0 < K; k0 += 32) {
#pragma unroll
    for (int i = 0; i < 2; ++i) {
      int f = tid + i * 256;
      int row = f >> 3;
      int kq  = f & 7;
      float4 vx = *reinterpret_cast<const float4*>(X + (r0 + row) * K + k0 + kq * 4);
      Xs[kq*4+0][row] = vx.x; Xs[kq*4+1][row] = vx.y;
      Xs[kq*4+2][row] = vx.z; Xs[kq*4+3][row] = vx.w;
      float4 vw = *reinterpret_cast<const float4*>(Wm + (o0 + row) * K + k0 + kq * 4);
      Ws[kq*4+0][row] = vw.x; Ws[kq*4+1][row] = vw.y;
      Ws[kq*4+2][row] = vw.z; Ws[kq*4+3][row] = vw.w;
    }
    __syncthreads();
#pragma unroll
    for (int k = 0; k < 32; ++k) {
      float xr[4], wc[4];
#pragma unroll
      for (int i = 0; i < 4; ++i) xr[i] = Xs[k][tr + 16*i];
#pragma unroll
      for (int j = 0; j < 4; ++j) wc[j] = Ws[k][tc + 16*j];
#pragma unroll
      for (int i = 0; i < 4; ++i)
#pragma unroll
        for (int j = 0; j < 4; ++j) acc[i][j] = fmaf(xr[i], wc[j], acc[i][j]);
    }
    __syncthreads();
  }
#pragma unroll
  for (int i = 0; i < 4; ++i) {
    long r = r0 + tr + 16*i;
#pragma unroll
    for (int j = 0; j < 4; ++j) {
      long o = o0 + tc + 16*j;
      Y[r * O + o] = acc[i][j] + bias[o];
    }
  }
}

__global__ void pool_mean(const float* __restrict__ X, float* __restrict__ Xp) {
  int idx = blockIdx.x * 256 + threadIdx.x;
  const int total = B_ * M_ * (C_ / 4);
  if (idx >= total) return;
  int row = idx / (C_ / 4);
  int cq  = idx % (C_ / 4);
  int b = row / M_, m = row % M_;
  const float4 va = reinterpret_cast<const float4*>(X + ((size_t)b * N_ + 2*m)     * C_)[cq];
  const float4 vb = reinterpret_cast<const float4*>(X + ((size_t)b * N_ + 2*m + 1) * C_)[cq];
  float4 r;
  r.x = 0.5f * (va.x + vb.x); r.y = 0.5f * (va.y + vb.y);
  r.z = 0.5f * (va.z + vb.z); r.w = 0.5f * (va.w + vb.w);
  reinterpret_cast<float4*>(Xp + (size_t)row * C_)[cq] = r;
}

__global__ __launch_bounds__(256) void ln_gelu_inplace(float* __restrict__ Xc,
                                                       const float* __restrict__ gam,
                                                       const float* __restrict__ bet) {
  const int row = blockIdx.x;
  float* p = Xc + (size_t)row * C_;
  const int t = threadIdx.x;
  float v0 = p[t], v1 = p[t + 256];
  float s  = wave_sum(v0 + v1);
  float ss = wave_sum(v0 * v0 + v1 * v1);
  __shared__ float rs[4], rss[4];
  const int w = t >> 6, lane = t & 63;
  if (lane == 0) { rs[w] = s; rss[w] = ss; }
  __syncthreads();
  float ts  = rs[0] + rs[1] + rs[2] + rs[3];
  float tss = rss[0] + rss[1] + rss[2] + rss[3];
  float mean = ts * (1.0f / C_);
  float var  = tss * (1.0f / C_) - mean * mean;
  float rstd = rsqrtf(var + LN_EPS_);
  float u0 = (v0 - mean) * rstd * gam[t]       + bet[t];
  float u1 = (v1 - mean) * rstd * gam[t + 256] + bet[t + 256];
  p[t]       = u0 * 0.5f * (1.0f + erff(u0 * 0.70710678118654752f));
  p[t + 256] = u1 * 0.5f * (1.0f + erff(u1 * 0.70710678118654752f));
}

// ---------------- MFMA bf16 flash attention ----------------
// Per-tile processing: NF key fragments of 16; MODE 0 = plain pooled tile,
// MODE 1 = local tile (group diagonal mask), MODE 2 = pooled tail (key>=M mask).
template<int NF, int MODE>
__device__ __forceinline__ void process_tile(
    const short* __restrict__ Ks, const short* __restrict__ Vt,
    short* __restrict__ Pw, bf16x8 qf0, bf16x8 qf1,
    float m_r[4], float l_r[4], f32x4 o[4],
    int g, int c0, const int* rq5, const int* cl5)
{
  float s[NF][4];
#pragma unroll
  for (int n = 0; n < NF; ++n) {
    f32x4 acc = {0.f, 0.f, 0.f, 0.f};
    bf16x8 k0 = *(const bf16x8*)&Ks[(n*16 + c0)*KSTR + g*8];
    bf16x8 k1 = *(const bf16x8*)&Ks[(n*16 + c0)*KSTR + g*8 + 32];
    acc = MFMA16(qf0, k0, acc);
    acc = MFMA16(qf1, k1, acc);
#pragma unroll
    for (int r = 0; r < 4; ++r) s[n][r] = acc[r];
  }
  if (MODE == 1) {
#pragma unroll
    for (int n = 0; n < NF; ++n)
#pragma unroll
      for (int r = 0; r < 4; ++r)
        if (rq5[r] != cl5[n]) s[n][r] = -3.0e38f;
  }
  if (MODE == 2) {
#pragma unroll
    for (int n = 0; n < NF; ++n) {
      if (960 + n*16 + c0 >= M_) {
#pragma unroll
        for (int r = 0; r < 4; ++r) s[n][r] = -3.0e38f;
      }
    }
  }
  float bm[4], al[4], rs[4];
#pragma unroll
  for (int r = 0; r < 4; ++r) {
    bm[r] = s[0][r];
#pragma unroll
    for (int n = 1; n < NF; ++n) bm[r] = fmaxf(bm[r], s[n][r]);
#pragma unroll
    for (int off = 1; off <= 8; off <<= 1)
      bm[r] = fmaxf(bm[r], __shfl_xor(bm[r], off));
    float mn = fmaxf(m_r[r], bm[r]);
    al[r] = __expf(m_r[r] - mn);
    m_r[r] = mn;
    rs[r] = 0.f;
  }
#pragma unroll
  for (int n = 0; n < NF; ++n)
#pragma unroll
    for (int r = 0; r < 4; ++r) {
      float p = __expf(s[n][r] - m_r[r]);
      short pb = f2bf(p);
      s[n][r] = __int_as_float((int)pb);      // stash bits
      rs[r] += bf2f(pb);                      // sum the bf16-rounded value
    }
#pragma unroll
  for (int r = 0; r < 4; ++r) {
#pragma unroll
    for (int off = 1; off <= 8; off <<= 1) rs[r] += __shfl_xor(rs[r], off);
    l_r[r] = l_r[r] * al[r] + rs[r];
  }
#pragma unroll
  for (int n = 0; n < 4; ++n) {
#pragma unroll
    for (int r = 0; r < 4; ++r) o[n][r] *= al[r];
  }
  // write P (bf16) to this wave's LDS buffer
#pragma unroll
  for (int n = 0; n < NF; ++n)
#pragma unroll
    for (int r = 0; r < 4; ++r)
      Pw[(g*4 + r)*PSTR + n*16 + c0] = (short)__float_as_int(s[n][r]);
  __asm__ volatile("s_waitcnt lgkmcnt(0)" ::: "memory");
  __builtin_amdgcn_sched_barrier(0);
  // PV
  constexpr int NC = (NF == 5) ? 3 : 2;
  bf16x8 pa[NC];
#pragma unroll
  for (int c = 0; c < NC; ++c)
    pa[c] = *(const bf16x8*)&Pw[c0*PSTR + g*8 + 32*c];
#pragma unroll
  for (int n = 0; n < 4; ++n) {
#pragma unroll
    for (int c = 0; c < NC; ++c) {
      bf16x8 vf = *(const bf16x8*)&Vt[(n*16 + c0)*VSTR + g*8 + 32*c];
      o[n] = MFMA16(pa[c], vf, o[n]);
    }
  }
}

__global__ __launch_bounds__(320) void attn_mfma(const float* __restrict__ Q,
                                                 const float* __restrict__ KV,
                                                 const float* __restrict__ KVP,
                                                 float* __restrict__ Oa) {
  __shared__ short Qs[TQ_ * KSTR];
  __shared__ short Ks[TQ_ * KSTR];
  __shared__ short Vt[64 * VSTR];          // [d][key], keys 0..95 used for local
  __shared__ short Pq[NW_ * 16 * PSTR];

  const int bid = blockIdx.x;
  const int b  = bid / (H_ * 25);
  const int h  = (bid / 25) % H_;
  const int n0 = (bid % 25) * TQ_;
  const int tid  = threadIdx.x;
  const int wq   = tid >> 6;
  const int lane = tid & 63;
  const int g    = lane >> 4;
  const int c0   = lane & 15;
  short* Pw = Pq + wq * 16 * PSTR;

  // ---- stage Q (scaled) : 80 rows x 64 d = 1280 float4 ----
#pragma unroll
  for (int i = 0; i < 4; ++i) {
    int flat = tid + i * 320;
    int row = flat >> 4, dq = flat & 15;
    float4 v = *(const float4*)(Q + ((size_t)(b * N_ + n0 + row)) * C_ + h * HD_ + dq * 4);
    v.x *= SCALE_; v.y *= SCALE_; v.z *= SCALE_; v.w *= SCALE_;
    *(uint2*)&Qs[row * KSTR + dq * 4] = pack4bf(v);
  }
  // ---- stage local K: the block's own 80 rows ----
#pragma unroll
  for (int i = 0; i < 4; ++i) {
    int flat = tid + i * 320;
    int key = flat >> 4, dq = flat & 15;
    float4 kk = *(const float4*)(KV + ((size_t)(b * N_ + n0 + key)) * (2 * C_) + h * HD_ + dq * 4);
    *(uint2*)&Ks[key * KSTR + dq * 4] = pack4bf(kk);
  }
  // ---- stage local V transposed (keys 0..79 data, 80..95 zero) ----
#pragma unroll
  for (int i = 0; i < 5; ++i) {
    int flat = tid + i * 320;
    if (flat < 1536) {
      int key = flat >> 4, dq = flat & 15;
      float4 vv = make_float4(0.f, 0.f, 0.f, 0.f);
      if (key < TQ_)
        vv = *(const float4*)(KV + ((size_t)(b * N_ + n0 + key)) * (2 * C_) + C_ + h * HD_ + dq * 4);
      Vt[(dq*4 + 0) * VSTR + key] = f2bf(vv.x);
      Vt[(dq*4 + 1) * VSTR + key] = f2bf(vv.y);
      Vt[(dq*4 + 2) * VSTR + key] = f2bf(vv.z);
      Vt[(dq*4 + 3) * VSTR + key] = f2bf(vv.w);
    }
  }
  // zero P pad columns 80..95 (read by local PV chunk c=2)
#pragma unroll
  for (int j = 0; j < 4; ++j)
    Pw[c0 * PSTR + 80 + g * 4 + j] = 0;
  __syncthreads();

  // hoist Q fragments
  bf16x8 qf0 = *(const bf16x8*)&Qs[(wq*16 + c0) * KSTR + g*8];
  bf16x8 qf1 = *(const bf16x8*)&Qs[(wq*16 + c0) * KSTR + g*8 + 32];

  int rq5[4], cl5[5];
#pragma unroll
  for (int r = 0; r < 4; ++r) rq5[r] = div5(wq*16 + g*4 + r);
#pragma unroll
  for (int n = 0; n < 5; ++n) cl5[n] = div5(n*16 + c0);

  float m_r[4] = {-3.0e38f, -3.0e38f, -3.0e38f, -3.0e38f};
  float l_r[4] = {0.f, 0.f, 0.f, 0.f};
  f32x4 o[4];
#pragma unroll
  for (int n = 0; n < 4; ++n) o[n] = (f32x4){0.f, 0.f, 0.f, 0.f};

  // ---- local tile: 80 keys, group-diagonal mask ----
  process_tile<5, 1>(Ks, Vt, Pw, qf0, qf1, m_r, l_r, o, g, c0, rq5, cl5);

  // ---- pooled tiles: 16 x 64 keys (last masked to 40) ----
  const float* kvp_b = KVP + (size_t)b * M_ * (2 * C_);
  for (int t = 0; t < 16; ++t) {
    __syncthreads();
    int m0 = t * 64;
#pragma unroll
    for (int i = 0; i < 4; ++i) {
      int flat = tid + i * 320;
      if (flat < 1024) {
        int key = flat >> 4, dq = flat & 15;
        int m = m0 + key;
        float4 kk = make_float4(0.f, 0.f, 0.f, 0.f);
        float4 vv = make_float4(0.f, 0.f, 0.f, 0.f);
        if (m < M_) {
          kk = *(const float4*)(kvp_b + (size_t)m * (2 * C_) + h * HD_ + dq * 4);
          vv = *(const float4*)(kvp_b + (size_t)m * (2 * C_) + C_ + h * HD_ + dq * 4);
        }
        *(uint2*)&Ks[key * KSTR + dq * 4] = pack4bf(kk);
        Vt[(dq*4 + 0) * VSTR + key] = f2bf(vv.x);
        Vt[(dq*4 + 1) * VSTR + key] = f2bf(vv.y);
        Vt[(dq*4 + 2) * VSTR + key] = f2bf(vv.z);
        Vt[(dq*4 + 3) * VSTR + key] = f2bf(vv.w);
      }
    }
    __syncthreads();
    if (t < 15) process_tile<4, 0>(Ks, Vt, Pw, qf0, qf1, m_r, l_r, o, g, c0, rq5, cl5);
    else        process_tile<4, 2>(Ks, Vt, Pw, qf0, qf1, m_r, l_r, o, g, c0, rq5, cl5);
  }

  // ---- epilogue: normalize + store ----
  float inv[4];
#pragma unroll
  for (int r = 0; r < 4; ++r) inv[r] = 1.0f / l_r[r];
#pragma unroll
  for (int n = 0; n < 4; ++n)
#pragma unroll
    for (int r = 0; r < 4; ++r) {
      int q = n0 + wq*16 + g*4 + r;
      Oa[((size_t)(b * N_ + q)) * C_ + h * HD_ + n*16 + c0] = o[n][r] * inv[r];
    }
}

extern "C" void kernel_launch(void* const* d_in, const int* in_sizes, int n_in,
                              void* d_out, int out_size, void* d_ws, size_t ws_size,
                              hipStream_t stream) {
  const float* x   = (const float*)d_in[0];
  const float* Wq  = (const float*)d_in[1];
  const float* bq  = (const float*)d_in[2];
  const float* Wkv = (const float*)d_in[3];
  const float* bkv = (const float*)d_in[4];
  const float* Wc  = (const float*)d_in[5];
  const float* bc  = (const float*)d_in[6];
  const float* lng = (const float*)d_in[7];
  const float* lnb = (const float*)d_in[8];
  const float* Wp  = (const float*)d_in[9];
  const float* bp  = (const float*)d_in[10];
  float* out = (float*)d_out;

  float* ws     = (float*)d_ws;
  float* q_buf  = ws;                              // 16000*512
  float* kv_buf = q_buf  + (size_t)16000 * 512;    // 16000*1024
  float* xpool  = kv_buf + (size_t)16000 * 1024;   // 8000*512
  float* xc     = xpool  + (size_t)8000  * 512;    // 8000*512
  float* kvp    = xc     + (size_t)8000  * 512;    // 8000*1024
  float* aout   = kvp    + (size_t)8000  * 1024;   // 16000*512

  dim3 blk(256);

  // pooled pre-path
  pool_mean<<<dim3((B_ * M_ * (C_/4) + 255) / 256), blk, 0, stream>>>(x, xpool);
  gemm_nt<<<dim3(C_/64, (B_*M_)/64), blk, 0, stream>>>(xpool, Wc, bc, xc, B_*M_, C_, C_);
  ln_gelu_inplace<<<dim3(B_*M_), blk, 0, stream>>>(xc, lng, lnb);
  gemm_nt<<<dim3((2*C_)/64, (B_*M_)/64), blk, 0, stream>>>(xc, Wkv, bkv, kvp, B_*M_, C_, 2*C_);

  // main projections
  gemm_nt<<<dim3(C_/64, (B_*N_)/64), blk, 0, stream>>>(x, Wq, bq, q_buf, B_*N_, C_, C_);
  gemm_nt<<<dim3((2*C_)/64, (B_*N_)/64), blk, 0, stream>>>(x, Wkv, bkv, kv_buf, B_*N_, C_, 2*C_);

  // fused MFMA attention (local 80-key tile + 16 pooled tiles, online softmax)
  attn_mfma<<<dim3(B_ * H_ * 25), dim3(320), 0, stream>>>(q_buf, kv_buf, kvp, aout);

  // output projection
  gemm_nt<<<dim3(C_/64, (B_*N_)/64), blk, 0, stream>>>(aout, Wp, bp, out, B_*N_, C_, C_);
}

// Round 3
// 350.002 us; speedup vs baseline: 8.7543x; 3.0542x over previous
//
#include <hip/hip_runtime.h>
#include <hip/hip_bf16.h>
#include <math.h>

// Problem constants
#define B_   8
#define N_   2000
#define C_   512
#define H_   8
#define W_   5
#define SR_  2
#define M_   1000      // N/SR
#define HD_  64        // C/H
#define KK_  512       // shared inner dim of every projection
#define RP_  8192      // padded row count for pooled path (8000 -> 8192)
#define LN_EPS_ 1e-5f
#define SCALE_  0.125f // hd^-0.5

// attention tiling
#define TQ_   80       // q rows per block (lcm(5,16)) -> 25 tiles
#define NW_   5        // waves per block
#define KSTR  72       // Ks/Qs LDS row stride in bf16
#define VSTR  104      // Vt LDS row stride in bf16
#define PSTR  104      // P LDS row stride in bf16

typedef __attribute__((ext_vector_type(8))) short bf16x8;
typedef __attribute__((ext_vector_type(4))) float f32x4;
#define MFMA16(a,b,c) __builtin_amdgcn_mfma_f32_16x16x32_bf16(a,b,c,0,0,0)

__device__ __forceinline__ short f2bf(float f) {
  unsigned u = __float_as_uint(f);
  u += 0x7FFFu + ((u >> 16) & 1u);
  return (short)(u >> 16);
}
__device__ __forceinline__ float bf2f(short s) {
  return __uint_as_float(((unsigned)(unsigned short)s) << 16);
}
__device__ __forceinline__ uint2 pack4bf(float4 v) {
  unsigned a = ((unsigned)(unsigned short)f2bf(v.x)) | (((unsigned)(unsigned short)f2bf(v.y)) << 16);
  unsigned b = ((unsigned)(unsigned short)f2bf(v.z)) | (((unsigned)(unsigned short)f2bf(v.w)) << 16);
  return make_uint2(a, b);
}
__device__ __forceinline__ int div5(int x) { return (x * 205) >> 10; }

__device__ __forceinline__ float wave_sum(float v) {
#pragma unroll
  for (int o = 32; o > 0; o >>= 1) v += __shfl_xor(v, o);
  return v;
}

__device__ __forceinline__ void gl_lds16(const void* g, void* l) {
  __builtin_amdgcn_global_load_lds(
      (const __attribute__((address_space(1))) void*)g,
      (__attribute__((address_space(3))) void*)l, 16, 0, 0);
}

// ---------------- fp32 -> bf16 convert (16B/thread) ----------------
__global__ __launch_bounds__(256) void cvt_bf16(const float* __restrict__ src,
                                                short* __restrict__ dst, int n8) {
  int i = blockIdx.x * 256 + threadIdx.x;
  if (i >= n8) return;
  float4 a = reinterpret_cast<const float4*>(src)[i * 2];
  float4 b = reinterpret_cast<const float4*>(src)[i * 2 + 1];
  uint2 pa = pack4bf(a), pb = pack4bf(b);
  reinterpret_cast<uint4*>(dst)[i] = make_uint4(pa.x, pa.y, pb.x, pb.y);
}

// ---------------- MFMA bf16 GEMM: Y = X(R,512) * W(O,512)^T + b ----------------
// R%128==0, O%128==0. OUT_BF16: 1 -> bf16 output, 0 -> fp32 output.
template<int OUT_BF16>
__global__ __launch_bounds__(256) void gemm_mfma(const short* __restrict__ A,
                                                 const short* __restrict__ Bm,
                                                 const float* __restrict__ bias,
                                                 void* __restrict__ Yv,
                                                 int O, float oscale) {
  __shared__ short As[128 * 32];
  __shared__ short Bs[128 * 32];
  const int tid  = threadIdx.x;
  const int w    = tid >> 6;
  const int lane = tid & 63;
  const int g    = lane >> 4;
  const int c0   = lane & 15;
  const int wr   = w >> 1;
  const int wc   = w & 1;
  const long r0 = (long)blockIdx.y * 128;
  const long o0 = (long)blockIdx.x * 128;
  const int srow = lane >> 2;          // 0..15 within wave's 16-row chunk
  const int scol = (lane & 3) * 8;     // bf16 col offset within BK=32

  f32x4 acc[4][4];
#pragma unroll
  for (int m = 0; m < 4; ++m)
#pragma unroll
    for (int n = 0; n < 4; ++n) acc[m][n] = (f32x4){0.f, 0.f, 0.f, 0.f};

  for (int kk = 0; kk < 16; ++kk) {
    __syncthreads();
#pragma unroll
    for (int i = 0; i < 2; ++i) {
      int arow = i * 64 + w * 16;
      gl_lds16(A  + (r0 + arow + srow) * KK_ + kk * 32 + scol, &As[arow * 32]);
      gl_lds16(Bm + (o0 + arow + srow) * KK_ + kk * 32 + scol, &Bs[arow * 32]);
    }
    __syncthreads();
    bf16x8 a[4], b[4];
#pragma unroll
    for (int m = 0; m < 4; ++m) a[m] = *(const bf16x8*)&As[(wr * 64 + m * 16 + c0) * 32 + g * 8];
#pragma unroll
    for (int n = 0; n < 4; ++n) b[n] = *(const bf16x8*)&Bs[(wc * 64 + n * 16 + c0) * 32 + g * 8];
#pragma unroll
    for (int m = 0; m < 4; ++m)
#pragma unroll
      for (int n = 0; n < 4; ++n) acc[m][n] = MFMA16(a[m], b[n], acc[m][n]);
  }

#pragma unroll
  for (int m = 0; m < 4; ++m) {
    long row = r0 + wr * 64 + m * 16 + g * 4;
#pragma unroll
    for (int n = 0; n < 4; ++n) {
      long col = o0 + wc * 64 + n * 16 + c0;
      float bv = bias[col];
#pragma unroll
      for (int r = 0; r < 4; ++r) {
        float v = (acc[m][n][r] + bv) * oscale;
        if (OUT_BF16) ((short*)Yv)[(row + r) * O + col] = f2bf(v);
        else          ((float*)Yv)[(row + r) * O + col] = v;
      }
    }
  }
}

// Xp[b*M+m][c] = 0.5*(x[b,2m,c] + x[b,2m+1,c]) -> bf16
__global__ void pool_mean(const float* __restrict__ X, short* __restrict__ Xp) {
  int idx = blockIdx.x * 256 + threadIdx.x;
  const int total = B_ * M_ * (C_ / 4);
  if (idx >= total) return;
  int row = idx / (C_ / 4);
  int cq  = idx % (C_ / 4);
  int b = row / M_, m = row % M_;
  const float4 va = reinterpret_cast<const float4*>(X + ((size_t)b * N_ + 2*m)     * C_)[cq];
  const float4 vb = reinterpret_cast<const float4*>(X + ((size_t)b * N_ + 2*m + 1) * C_)[cq];
  float4 r;
  r.x = 0.5f * (va.x + vb.x); r.y = 0.5f * (va.y + vb.y);
  r.z = 0.5f * (va.z + vb.z); r.w = 0.5f * (va.w + vb.w);
  reinterpret_cast<uint2*>(Xp + (size_t)row * C_)[cq] = pack4bf(r);
}

// LayerNorm + exact GELU: fp32 in -> bf16 out, rows of 512
__global__ __launch_bounds__(256) void ln_gelu(const float* __restrict__ Xc,
                                               short* __restrict__ Xo,
                                               const float* __restrict__ gam,
                                               const float* __restrict__ bet) {
  const int row = blockIdx.x;
  const float* p = Xc + (size_t)row * C_;
  const int t = threadIdx.x;
  float v0 = p[t], v1 = p[t + 256];
  float s  = wave_sum(v0 + v1);
  float ss = wave_sum(v0 * v0 + v1 * v1);
  __shared__ float rs[4], rss[4];
  const int w = t >> 6, lane = t & 63;
  if (lane == 0) { rs[w] = s; rss[w] = ss; }
  __syncthreads();
  float ts  = rs[0] + rs[1] + rs[2] + rs[3];
  float tss = rss[0] + rss[1] + rss[2] + rss[3];
  float mean = ts * (1.0f / C_);
  float var  = tss * (1.0f / C_) - mean * mean;
  float rstd = rsqrtf(var + LN_EPS_);
  float u0 = (v0 - mean) * rstd * gam[t]       + bet[t];
  float u1 = (v1 - mean) * rstd * gam[t + 256] + bet[t + 256];
  Xo[(size_t)row * C_ + t]       = f2bf(u0 * 0.5f * (1.0f + erff(u0 * 0.70710678118654752f)));
  Xo[(size_t)row * C_ + t + 256] = f2bf(u1 * 0.5f * (1.0f + erff(u1 * 0.70710678118654752f)));
}

// ---------------- MFMA bf16 flash attention (bf16 inputs, bf16 output) ----------------
template<int NF, int MODE>
__device__ __forceinline__ void process_tile(
    const short* __restrict__ Ks, const short* __restrict__ Vt,
    short* __restrict__ Pw, bf16x8 qf0, bf16x8 qf1,
    float m_r[4], float l_r[4], f32x4 o[4],
    int g, int c0, const int* rq5, const int* cl5)
{
  float s[NF][4];
#pragma unroll
  for (int n = 0; n < NF; ++n) {
    f32x4 acc = {0.f, 0.f, 0.f, 0.f};
    bf16x8 k0 = *(const bf16x8*)&Ks[(n*16 + c0)*KSTR + g*8];
    bf16x8 k1 = *(const bf16x8*)&Ks[(n*16 + c0)*KSTR + g*8 + 32];
    acc = MFMA16(qf0, k0, acc);
    acc = MFMA16(qf1, k1, acc);
#pragma unroll
    for (int r = 0; r < 4; ++r) s[n][r] = acc[r];
  }
  if (MODE == 1) {
#pragma unroll
    for (int n = 0; n < NF; ++n)
#pragma unroll
      for (int r = 0; r < 4; ++r)
        if (rq5[r] != cl5[n]) s[n][r] = -3.0e38f;
  }
  if (MODE == 2) {
#pragma unroll
    for (int n = 0; n < NF; ++n) {
      if (960 + n*16 + c0 >= M_) {
#pragma unroll
        for (int r = 0; r < 4; ++r) s[n][r] = -3.0e38f;
      }
    }
  }
  float bm[4], al[4], rsum[4];
#pragma unroll
  for (int r = 0; r < 4; ++r) {
    bm[r] = s[0][r];
#pragma unroll
    for (int n = 1; n < NF; ++n) bm[r] = fmaxf(bm[r], s[n][r]);
#pragma unroll
    for (int off = 1; off <= 8; off <<= 1)
      bm[r] = fmaxf(bm[r], __shfl_xor(bm[r], off));
    float mn = fmaxf(m_r[r], bm[r]);
    al[r] = __expf(m_r[r] - mn);
    m_r[r] = mn;
    rsum[r] = 0.f;
  }
#pragma unroll
  for (int n = 0; n < NF; ++n)
#pragma unroll
    for (int r = 0; r < 4; ++r) {
      float p = __expf(s[n][r] - m_r[r]);
      short pb = f2bf(p);
      s[n][r] = __int_as_float((int)pb);
      rsum[r] += bf2f(pb);
    }
#pragma unroll
  for (int r = 0; r < 4; ++r) {
#pragma unroll
    for (int off = 1; off <= 8; off <<= 1) rsum[r] += __shfl_xor(rsum[r], off);
    l_r[r] = l_r[r] * al[r] + rsum[r];
  }
#pragma unroll
  for (int n = 0; n < 4; ++n) {
#pragma unroll
    for (int r = 0; r < 4; ++r) o[n][r] *= al[r];
  }
#pragma unroll
  for (int n = 0; n < NF; ++n)
#pragma unroll
    for (int r = 0; r < 4; ++r)
      Pw[(g*4 + r)*PSTR + n*16 + c0] = (short)__float_as_int(s[n][r]);
  __asm__ volatile("s_waitcnt lgkmcnt(0)" ::: "memory");
  __builtin_amdgcn_sched_barrier(0);
  constexpr int NC = (NF == 5) ? 3 : 2;
  bf16x8 pa[NC];
#pragma unroll
  for (int c = 0; c < NC; ++c)
    pa[c] = *(const bf16x8*)&Pw[c0*PSTR + g*8 + 32*c];
#pragma unroll
  for (int n = 0; n < 4; ++n) {
#pragma unroll
    for (int c = 0; c < NC; ++c) {
      bf16x8 vf = *(const bf16x8*)&Vt[(n*16 + c0)*VSTR + g*8 + 32*c];
      o[n] = MFMA16(pa[c], vf, o[n]);
    }
  }
}

__global__ __launch_bounds__(320) void attn_mfma(const short* __restrict__ Q,
                                                 const short* __restrict__ KV,
                                                 const short* __restrict__ KVP,
                                                 short* __restrict__ Oa) {
  __shared__ short Qs[TQ_ * KSTR];
  __shared__ short Ks[TQ_ * KSTR];
  __shared__ short Vt[64 * VSTR];
  __shared__ short Pq[NW_ * 16 * PSTR];

  const int bid = blockIdx.x;
  const int b  = bid / (H_ * 25);
  const int h  = (bid / 25) % H_;
  const int n0 = (bid % 25) * TQ_;
  const int tid  = threadIdx.x;
  const int wq   = tid >> 6;
  const int lane = tid & 63;
  const int g    = lane >> 4;
  const int c0   = lane & 15;
  short* Pw = Pq + wq * 16 * PSTR;
  const bf16x8 ZV = {0,0,0,0,0,0,0,0};

  // stage Q (pre-scaled bf16): 80 rows x 8 octets
#pragma unroll
  for (int i = 0; i < 2; ++i) {
    int flat = tid + i * 320;
    int row = flat >> 3, dq = flat & 7;
    bf16x8 v = *(const bf16x8*)(Q + ((size_t)(b * N_ + n0 + row)) * C_ + h * HD_ + dq * 8);
    *(bf16x8*)&Qs[row * KSTR + dq * 8] = v;
  }
  // stage local K: block's own 80 rows
#pragma unroll
  for (int i = 0; i < 2; ++i) {
    int flat = tid + i * 320;
    int row = flat >> 3, dq = flat & 7;
    bf16x8 v = *(const bf16x8*)(KV + ((size_t)(b * N_ + n0 + row)) * (2 * C_) + h * HD_ + dq * 8);
    *(bf16x8*)&Ks[row * KSTR + dq * 8] = v;
  }
  // stage local V transposed (keys 0..79 data, 80..95 zero)
#pragma unroll
  for (int i = 0; i < 3; ++i) {
    int flat = tid + i * 320;
    if (flat < 768) {
      int key = flat >> 3, dq = flat & 7;
      bf16x8 v = ZV;
      if (key < TQ_)
        v = *(const bf16x8*)(KV + ((size_t)(b * N_ + n0 + key)) * (2 * C_) + C_ + h * HD_ + dq * 8);
#pragma unroll
      for (int e = 0; e < 8; ++e) Vt[(dq*8 + e) * VSTR + key] = v[e];
    }
  }
#pragma unroll
  for (int j = 0; j < 4; ++j)
    Pw[c0 * PSTR + 80 + g * 4 + j] = 0;
  __syncthreads();

  bf16x8 qf0 = *(const bf16x8*)&Qs[(wq*16 + c0) * KSTR + g*8];
  bf16x8 qf1 = *(const bf16x8*)&Qs[(wq*16 + c0) * KSTR + g*8 + 32];

  int rq5[4], cl5[5];
#pragma unroll
  for (int r = 0; r < 4; ++r) rq5[r] = div5(wq*16 + g*4 + r);
#pragma unroll
  for (int n = 0; n < 5; ++n) cl5[n] = div5(n*16 + c0);

  float m_r[4] = {-3.0e38f, -3.0e38f, -3.0e38f, -3.0e38f};
  float l_r[4] = {0.f, 0.f, 0.f, 0.f};
  f32x4 o[4];
#pragma unroll
  for (int n = 0; n < 4; ++n) o[n] = (f32x4){0.f, 0.f, 0.f, 0.f};

  process_tile<5, 1>(Ks, Vt, Pw, qf0, qf1, m_r, l_r, o, g, c0, rq5, cl5);

  const short* kvp_b = KVP + (size_t)b * M_ * (2 * C_);
  for (int t = 0; t < 16; ++t) {
    __syncthreads();
    int m0 = t * 64;
#pragma unroll
    for (int i = 0; i < 2; ++i) {
      int flat = tid + i * 320;
      if (flat < 512) {
        int key = flat >> 3, dq = flat & 7;
        int m = m0 + key;
        bf16x8 kk = ZV, vv = ZV;
        if (m < M_) {
          kk = *(const bf16x8*)(kvp_b + (size_t)m * (2 * C_) + h * HD_ + dq * 8);
          vv = *(const bf16x8*)(kvp_b + (size_t)m * (2 * C_) + C_ + h * HD_ + dq * 8);
        }
        *(bf16x8*)&Ks[key * KSTR + dq * 8] = kk;
#pragma unroll
        for (int e = 0; e < 8; ++e) Vt[(dq*8 + e) * VSTR + key] = vv[e];
      }
    }
    __syncthreads();
    if (t < 15) process_tile<4, 0>(Ks, Vt, Pw, qf0, qf1, m_r, l_r, o, g, c0, rq5, cl5);
    else        process_tile<4, 2>(Ks, Vt, Pw, qf0, qf1, m_r, l_r, o, g, c0, rq5, cl5);
  }

  float inv[4];
#pragma unroll
  for (int r = 0; r < 4; ++r) inv[r] = 1.0f / l_r[r];
#pragma unroll
  for (int n = 0; n < 4; ++n)
#pragma unroll
    for (int r = 0; r < 4; ++r) {
      int q = n0 + wq*16 + g*4 + r;
      Oa[((size_t)(b * N_ + q)) * C_ + h * HD_ + n*16 + c0] = f2bf(o[n][r] * inv[r]);
    }
}

extern "C" void kernel_launch(void* const* d_in, const int* in_sizes, int n_in,
                              void* d_out, int out_size, void* d_ws, size_t ws_size,
                              hipStream_t stream) {
  const float* x   = (const float*)d_in[0];
  const float* Wq  = (const float*)d_in[1];
  const float* bq  = (const float*)d_in[2];
  const float* Wkv = (const float*)d_in[3];
  const float* bkv = (const float*)d_in[4];
  const float* Wc  = (const float*)d_in[5];
  const float* bc  = (const float*)d_in[6];
  const float* lng = (const float*)d_in[7];
  const float* lnb = (const float*)d_in[8];
  const float* Wp  = (const float*)d_in[9];
  const float* bp  = (const float*)d_in[10];
  float* out = (float*)d_out;

  // workspace layout: fp32 region first, then bf16 regions (all 16B aligned)
  float* xc   = (float*)d_ws;                         // RP_*512 fp32
  short* sb   = (short*)(xc + (size_t)RP_ * 512);
  short* xb    = sb;                                  // 16000*512
  short* qb    = xb   + (size_t)16000 * 512;          // 16000*512 (pre-scaled)
  short* kvb   = qb   + (size_t)16000 * 512;          // 16000*1024
  short* xpb   = kvb  + (size_t)16000 * 1024;         // RP_*512
  short* xcb   = xpb  + (size_t)RP_ * 512;            // RP_*512
  short* kvpb  = xcb  + (size_t)RP_ * 512;            // RP_*1024
  short* aoutb = kvpb + (size_t)RP_ * 1024;           // 16000*512
  short* Wqb   = aoutb + (size_t)16000 * 512;         // 512*512
  short* Wkvb  = Wqb  + (size_t)512 * 512;            // 1024*512
  short* Wcb   = Wkvb + (size_t)1024 * 512;           // 512*512
  short* Wpb   = Wcb  + (size_t)512 * 512;            // 512*512

  dim3 blk(256);

  // converts
  cvt_bf16<<<dim3((16000*512/8 + 255)/256), blk, 0, stream>>>(x,   xb,   16000*512/8);
  cvt_bf16<<<dim3((512*512/8   + 255)/256), blk, 0, stream>>>(Wq,  Wqb,  512*512/8);
  cvt_bf16<<<dim3((1024*512/8  + 255)/256), blk, 0, stream>>>(Wkv, Wkvb, 1024*512/8);
  cvt_bf16<<<dim3((512*512/8   + 255)/256), blk, 0, stream>>>(Wc,  Wcb,  512*512/8);
  cvt_bf16<<<dim3((512*512/8   + 255)/256), blk, 0, stream>>>(Wp,  Wpb,  512*512/8);

  // pooled pre-path
  pool_mean<<<dim3((B_ * M_ * (C_/4) + 255)/256), blk, 0, stream>>>(x, xpb);
  gemm_mfma<0><<<dim3(C_/128, RP_/128), blk, 0, stream>>>(xpb, Wcb, bc, xc, C_, 1.0f);
  ln_gelu<<<dim3(B_ * M_), blk, 0, stream>>>(xc, xcb, lng, lnb);
  gemm_mfma<1><<<dim3((2*C_)/128, RP_/128), blk, 0, stream>>>(xcb, Wkvb, bkv, kvpb, 2*C_, 1.0f);

  // main projections (q pre-scaled by hd^-0.5)
  gemm_mfma<1><<<dim3(C_/128, 16000/128), blk, 0, stream>>>(xb, Wqb, bq, qb, C_, SCALE_);
  gemm_mfma<1><<<dim3((2*C_)/128, 16000/128), blk, 0, stream>>>(xb, Wkvb, bkv, kvb, 2*C_, 1.0f);

  // fused MFMA attention
  attn_mfma<<<dim3(B_ * H_ * 25), dim3(320), 0, stream>>>(qb, kvb, kvpb, aoutb);

  // output projection (fp32 out)
  gemm_mfma<0><<<dim3(C_/128, 16000/128), blk, 0, stream>>>(aoutb, Wpb, bp, out, C_, 1.0f);
}